// Round 1
// baseline (284.102 us; speedup 1.0000x reference)
//
#include <hip/hip_runtime.h>
#include <math.h>

// Problem constants (from reference): NT=64, NR=4, DK=2, KU=8, BR=16, BATCH=256
// channel:    [B][64][4][16][16]  (last dim: 8 real then 8 imag)   = 65536 f32/batch
// prediction: [B][2560] = U (2048: [4][2][16][16], re/im split) ++ W (512: [2][2][16][8])
// out:        [B][64][2][8][2] f32 (re,im) = 2048 f32/batch

namespace {

struct P1 {
    float2 HHU[64][17];   // [t][d*8+k], padded
    float2 T[64][17];     // [t][e*8+k], padded
};
union ShU {
    P1 p1;
    float2 Aug[64][81];   // [row][col], 64 matrix cols + 16 RHS, padded stride 81
};

} // namespace

__global__ __launch_bounds__(256)
void uw2v_kernel(const float* __restrict__ channel,
                 const float* __restrict__ prediction,
                 float2* __restrict__ out)
{
    __shared__ ShU sh;
    __shared__ float2 U_s[4][2][16][8];   // [r][d][f][k]
    __shared__ float  W_s[2][2][16][8];   // [d][e][f][k]
    __shared__ float2 HUW[64][16];        // [t][e*8+k]
    __shared__ float2 redbuf[4];
    __shared__ float  fred[4];
    __shared__ int    pivot_sh;
    __shared__ float2 ipv_sh;

    const int b   = blockIdx.x;
    const int tid = threadIdx.x;
    const float* pred = prediction + (size_t)b * 2560;
    const float* chan = channel + (size_t)b * 65536;

    // ---- load U (1024 complex) and W (512 f32); zero HUW ----
    #pragma unroll
    for (int i = 0; i < 4; ++i) {
        int m = tid + i * 256;                  // linear [r][d][f][k]
        int r = m >> 8, d = (m >> 7) & 1, f = (m >> 3) & 15, k = m & 7;
        const float* src = pred + (((r * 2 + d) * 16 + f) << 4);
        ((float2*)U_s)[m] = make_float2(src[k], src[k + 8]);
        ((float2*)HUW)[m] = make_float2(0.f, 0.f);
    }
    #pragma unroll
    for (int i = 0; i < 2; ++i) {
        int m = tid + i * 256;
        ((float*)W_s)[m] = pred[2048 + m];
    }
    __syncthreads();

    const int t4 = tid >> 2, r4 = tid & 3;                       // HHU mapping
    const int tq = (tid >> 4) << 2, sq = (tid & 15) << 2;        // quad 4x4 tile

    float2 qacc[4][4];
    #pragma unroll
    for (int i = 0; i < 4; ++i)
        #pragma unroll
        for (int j = 0; j < 4; ++j) qacc[i][j] = make_float2(0.f, 0.f);
    float2 tracc = make_float2(0.f, 0.f);

    #pragma unroll 1
    for (int f = 0; f < 16; ++f) {
        // ---- HHU[t][d][k] = sum_r conj(H[t][r][f][k]) * U[r][d][f][k] ----
        const float4* hp = (const float4*)(chan + (((t4 * 4 + r4) * 16 + f) << 4));
        float4 ha = hp[0], hb = hp[1], hc = hp[2], hd = hp[3];
        float hre[8] = {ha.x, ha.y, ha.z, ha.w, hb.x, hb.y, hb.z, hb.w};
        float him[8] = {hc.x, hc.y, hc.z, hc.w, hd.x, hd.y, hd.z, hd.w};
        float2 part[16];
        #pragma unroll
        for (int d = 0; d < 2; ++d)
            #pragma unroll
            for (int k = 0; k < 8; ++k) {
                float2 u = U_s[r4][d][f][k];
                part[d * 8 + k] = make_float2(hre[k] * u.x + him[k] * u.y,
                                              hre[k] * u.y - him[k] * u.x);
            }
        #pragma unroll
        for (int m = 0; m < 16; ++m) {
            part[m].x += __shfl_xor(part[m].x, 1);
            part[m].y += __shfl_xor(part[m].y, 1);
            part[m].x += __shfl_xor(part[m].x, 2);
            part[m].y += __shfl_xor(part[m].y, 2);
        }
        if (r4 == 0) {
            #pragma unroll
            for (int m = 0; m < 16; ++m) sh.p1.HHU[t4][m] = part[m];
        }
        // ---- tr_UWU partial (independent of HHU) ----
        if (tid < 128) {
            int r = tid >> 5, d = (tid >> 4) & 1, e = (tid >> 3) & 1, k = tid & 7;
            float w = W_s[d][e][f][k];
            float2 u1 = U_s[r][d][f][k], u2 = U_s[r][e][f][k];
            tracc.x += w * (u1.x * u2.x + u1.y * u2.y);
            tracc.y += w * (u1.y * u2.x - u1.x * u2.y);
        }
        __syncthreads();

        // ---- T[t][e][k] = sum_d HHU[t][d][k] * W[d][e][f][k];  HUW += T ----
        #pragma unroll
        for (int i = 0; i < 4; ++i) {
            int m = tid + i * 256;
            int t = m >> 4, e = (m >> 3) & 1, k = m & 7;
            float w0 = W_s[0][e][f][k], w1 = W_s[1][e][f][k];
            float2 h0 = sh.p1.HHU[t][k], h1 = sh.p1.HHU[t][8 + k];
            float2 tv = make_float2(h0.x * w0 + h1.x * w1, h0.y * w0 + h1.y * w1);
            sh.p1.T[t][e * 8 + k] = tv;
            float2 acc = HUW[t][e * 8 + k];
            acc.x += tv.x; acc.y += tv.y;
            HUW[t][e * 8 + k] = acc;
        }
        __syncthreads();

        // ---- quad[t][s] += sum_m T[t][m] * conj(HHU[s][m]) ----
        #pragma unroll
        for (int m = 0; m < 16; ++m) {
            float2 tv[4], hv[4];
            #pragma unroll
            for (int i = 0; i < 4; ++i) tv[i] = sh.p1.T[tq + i][m];
            #pragma unroll
            for (int j = 0; j < 4; ++j) hv[j] = sh.p1.HHU[sq + j][m];
            #pragma unroll
            for (int i = 0; i < 4; ++i)
                #pragma unroll
                for (int j = 0; j < 4; ++j) {
                    qacc[i][j].x += tv[i].x * hv[j].x + tv[i].y * hv[j].y;
                    qacc[i][j].y += tv[i].y * hv[j].x - tv[i].x * hv[j].y;
                }
        }
        __syncthreads();
    }

    // ---- reduce tr_UWU across block ----
    #pragma unroll
    for (int off = 32; off; off >>= 1) {
        tracc.x += __shfl_xor(tracc.x, off);
        tracc.y += __shfl_xor(tracc.y, off);
    }
    if ((tid & 63) == 0) redbuf[tid >> 6] = tracc;
    __syncthreads();
    float2 trv;
    trv.x = 0.1f * (redbuf[0].x + redbuf[1].x + redbuf[2].x + redbuf[3].x);
    trv.y = 0.1f * (redbuf[0].y + redbuf[1].y + redbuf[2].y + redbuf[3].y);

    // ---- build augmented system: Aug = [quad + trv*I | HUW] (overwrites union) ----
    #pragma unroll
    for (int i = 0; i < 4; ++i)
        #pragma unroll
        for (int j = 0; j < 4; ++j) {
            float2 v = qacc[i][j];
            if (tq + i == sq + j) { v.x += trv.x; v.y += trv.y; }
            sh.Aug[tq + i][sq + j] = v;
        }
    #pragma unroll
    for (int i = 0; i < 4; ++i) {
        int m = tid + i * 256;
        int t = m >> 4, c = m & 15;
        sh.Aug[t][64 + c] = HUW[t][c];
    }
    __syncthreads();

    // ---- Gauss-Jordan with partial pivoting ----
    #pragma unroll 1
    for (int ks = 0; ks < 64; ++ks) {
        if (tid < 64) {  // wave 0: argmax pivot + broadcast 1/pivot
            float2 a = sh.Aug[tid][ks];
            float mag = (tid >= ks) ? (a.x * a.x + a.y * a.y) : -1.0f;
            int idx = tid;
            #pragma unroll
            for (int off = 32; off; off >>= 1) {
                float om = __shfl_xor(mag, off);
                int   oi = __shfl_xor(idx, off);
                if (om > mag) { mag = om; idx = oi; }
            }
            float px = __shfl(a.x, idx);
            float py = __shfl(a.y, idx);
            if (tid == 0) {
                pivot_sh = idx;
                float inv = 1.0f / (px * px + py * py);
                ipv_sh = make_float2(px * inv, -py * inv);
            }
        }
        __syncthreads();
        const int p = pivot_sh;
        const float2 ipv = ipv_sh;
        if (tid < 80) {  // swap rows ks<->p, scale row ks by 1/pivot
            float2 a  = sh.Aug[ks][tid];
            float2 bb = sh.Aug[p][tid];
            sh.Aug[ks][tid] = make_float2(bb.x * ipv.x - bb.y * ipv.y,
                                          bb.x * ipv.y + bb.y * ipv.x);
            if (p != ks) sh.Aug[p][tid] = a;
        }
        __syncthreads();
        {   // eliminate column ks from all other rows
            int i = tid >> 2;
            if (i != ks) {
                float2 L = sh.Aug[i][ks];
                for (int j = ks + 1 + (tid & 3); j < 80; j += 4) {
                    float2 pr = sh.Aug[ks][j];
                    float2 v  = sh.Aug[i][j];
                    v.x -= L.x * pr.x - L.y * pr.y;
                    v.y -= L.x * pr.y + L.y * pr.x;
                    sh.Aug[i][j] = v;
                }
            }
        }
        __syncthreads();
    }

    // ---- normalize and write out ----
    float ss = 0.f;
    float2 xs[4];
    #pragma unroll
    for (int i = 0; i < 4; ++i) {
        int m = tid + i * 256;
        int t = m >> 4, c = m & 15;
        float2 v = sh.Aug[t][64 + c];
        xs[i] = v;
        ss += v.x * v.x + v.y * v.y;
    }
    #pragma unroll
    for (int off = 32; off; off >>= 1) ss += __shfl_xor(ss, off);
    if ((tid & 63) == 0) fred[tid >> 6] = ss;
    __syncthreads();
    float total = fred[0] + fred[1] + fred[2] + fred[3];
    float invn = 1.0f / sqrtf(total);
    #pragma unroll
    for (int i = 0; i < 4; ++i) {
        int m = tid + i * 256;
        out[(size_t)b * 1024 + m] = make_float2(xs[i].x * invn, xs[i].y * invn);
    }
}

extern "C" void kernel_launch(void* const* d_in, const int* in_sizes, int n_in,
                              void* d_out, int out_size, void* d_ws, size_t ws_size,
                              hipStream_t stream) {
    const float* channel    = (const float*)d_in[0];
    const float* prediction = (const float*)d_in[1];
    int batch = in_sizes[0] / 65536;   // 256
    uw2v_kernel<<<dim3(batch), dim3(256), 0, stream>>>(channel, prediction,
                                                       (float2*)d_out);
}